// Round 2
// baseline (352.736 us; speedup 1.0000x reference)
//
#include <hip/hip_runtime.h>

// db1 inverse wavelet transform (grouped transposed conv, k=2, stride=2).
// x: (B=16, C=128, H=128, W=128) fp32 -> out: (B=16, G=64, 256, 256) fp32.
// out[b,g,2h+i,2w+j] = x[b,2g,h,w]*f0[i][j] + x[b,2g+1,h,w]*f1[i][j]
//
// Memory-bound streaming op: 128 MiB read + 256 MiB write -> ~63 us at the
// fill-measured 6.4 TB/s.
// R2 post-mortem: NT-hint removal was perf-neutral -> cache policy is not
// the limiter. R3: attack memory-level parallelism. Old kernel: 2 dependent
// 8B loads/thread (minimum MLP), 32768 blocks. New: each thread owns a
// 2-wide x 4-row input patch -> 8 independent 8B loads issued back-to-back,
// then 8 stores, 8192 blocks. Wave-level coalescing is IDENTICAL (every
// store instruction still writes one full, aligned 1KiB output row; loads
// still 512B-contiguous per wave) -- only per-thread outstanding-request
// count (2->8) and block count change. If dur_us is unchanged, the kernel
// is at its roofline and the 345us plateau is harness fixed cost (1GiB
// poison fill ~166us + resets + graph gaps).

typedef float v2f __attribute__((ext_vector_type(2)));
typedef float v4f __attribute__((ext_vector_type(4)));

__global__ __launch_bounds__(256) void iwt_kernel(
    const float* __restrict__ x,
    const float* __restrict__ filt,
    float* __restrict__ out)
{
    constexpr int H = 128, W = 128;
    constexpr int HW = H * W;                 // 16384
    constexpr int OPLANE = (2 * H) * (2 * W); // 65536
    constexpr int OW = 2 * W;                 // 256

    int tid = blockIdx.x * blockDim.x + threadIdx.x; // 0 .. 2097151
    int tw = tid & 63;            // w-pair index, W2=64
    int hq = (tid >> 6) & 31;     // h-quad index: rows 4hq .. 4hq+3
    int bg = tid >> 11;           // b*G + g, 0..1023

    // channel plane index of x0 = b*C + 2g = 2*bg
    int x0off = (2 * bg) * HW + (4 * hq) * W + 2 * tw;

    // 8 independent loads, issued back-to-back (4 rows x 2 channels).
    v2f x0v[4], x1v[4];
#pragma unroll
    for (int r = 0; r < 4; ++r) {
        x0v[r] = *(const v2f*)(x + x0off + r * W);
        x1v[r] = *(const v2f*)(x + x0off + r * W + HW);
    }

    // filters: f0[i][j] = filt[i*2+j], f1[i][j] = filt[4+i*2+j]
    // uniform address -> scalar loads, hoisted
    float f000 = filt[0], f001 = filt[1], f010 = filt[2], f011 = filt[3];
    float f100 = filt[4], f101 = filt[5], f110 = filt[6], f111 = filt[7];

    int ooff = bg * OPLANE + (8 * hq) * OW + 4 * tw;

#pragma unroll
    for (int r = 0; r < 4; ++r) {
        const v2f x0 = x0v[r];
        const v2f x1 = x1v[r];
        v4f r0, r1;
        r0.x = x0.x * f000 + x1.x * f100;
        r0.y = x0.x * f001 + x1.x * f101;
        r0.z = x0.y * f000 + x1.y * f100;
        r0.w = x0.y * f001 + x1.y * f101;

        r1.x = x0.x * f010 + x1.x * f110;
        r1.y = x0.x * f011 + x1.x * f111;
        r1.z = x0.y * f010 + x1.y * f110;
        r1.w = x0.y * f011 + x1.y * f111;

        // Each wave store instruction covers one full aligned 1KiB row.
        *(v4f*)(out + ooff + (2 * r) * OW) = r0;
        *(v4f*)(out + ooff + (2 * r + 1) * OW) = r1;
    }
}

extern "C" void kernel_launch(void* const* d_in, const int* in_sizes, int n_in,
                              void* d_out, int out_size, void* d_ws, size_t ws_size,
                              hipStream_t stream) {
    const float* x    = (const float*)d_in[0];
    const float* filt = (const float*)d_in[1];
    float* out        = (float*)d_out;

    // total threads = 16*64*32*64 = 2097152 (4 rows per thread)
    constexpr int total = 16 * 64 * 32 * 64;
    constexpr int block = 256;
    iwt_kernel<<<total / block, block, 0, stream>>>(x, filt, out);
}